// Round 1
// 217.960 us; speedup vs baseline: 1.1183x; 1.1183x over previous
//
#include <hip/hip_runtime.h>

#define BB 16
#define NN 2048
#define DD 128

typedef __attribute__((ext_vector_type(8))) __bf16 bf16x8;
typedef __attribute__((ext_vector_type(4))) float f32x4;
typedef __attribute__((ext_vector_type(4))) unsigned int u32x4;
typedef __attribute__((address_space(3))) unsigned int lds_u32;
typedef __attribute__((address_space(1))) const unsigned int glob_u32;

static __device__ __forceinline__ unsigned short f2b(float f) {
  union { float f; unsigned int u; } c; c.f = f;
  unsigned int u = c.u;
  unsigned int r = (u + 0x7FFFu + ((u >> 16) & 1u)) >> 16;
  return (unsigned short)r;
}

// WT[l][e][d] = bf16(W[l][d][e])  -- 96 KB total, L2-resident afterwards
__global__ void k_wt(const float* __restrict__ W, unsigned short* __restrict__ WT) {
  __shared__ float t[64][65];
  int l = blockIdx.z, d0 = blockIdx.x * 64, e0 = blockIdx.y * 64;
  int tid = threadIdx.x;
  const float* src = W + (size_t)l * DD * DD;
  for (int p = 0; p < 16; ++p) {
    int idx = p * 256 + tid;
    int d = idx >> 6, e = idx & 63;
    t[e][d] = src[(size_t)(d0 + d) * DD + (e0 + e)];
  }
  __syncthreads();
  unsigned short* dst = WT + (size_t)l * DD * DD;
  for (int p = 0; p < 4; ++p) {
    int idx = p * 256 + tid;
    int e = idx >> 4, d4 = (idx & 15) * 4;
    ushort4 r;
    r.x = f2b(t[e][d4 + 0]); r.y = f2b(t[e][d4 + 1]);
    r.z = f2b(t[e][d4 + 2]); r.w = f2b(t[e][d4 + 3]);
    *(ushort4*)(dst + (size_t)(e0 + e) * DD + (d0 + d4)) = r;
  }
}

// Merged: x<1024 -> adj transpose tile; x>=1024 -> layer-0 gemm1 (X fp32, WT global frags)
__global__ __launch_bounds__(256) void k_pre(const float* __restrict__ adj,
                                             unsigned short* __restrict__ adjT,
                                             const float* __restrict__ X,
                                             const unsigned short* __restrict__ WT,
                                             unsigned short* __restrict__ hwT) {
  int b = blockIdx.y, x = blockIdx.x, tid = threadIdx.x;
  if (x < 1024) {
    __shared__ float t[64][65];
    int j0 = (x >> 5) * 64, i0 = (x & 31) * 64;
    const float* src = adj + (size_t)b * NN * NN;
    for (int p = 0; p < 16; ++p) {
      int idx = p * 256 + tid;
      int i = idx >> 6, j = idx & 63;
      t[j][i] = src[(size_t)(i0 + i) * NN + (j0 + j)];
    }
    __syncthreads();
    unsigned short* dst = adjT + (size_t)b * NN * NN;
    for (int p = 0; p < 4; ++p) {
      int idx = p * 256 + tid;
      int j = idx >> 4, i4 = (idx & 15) * 4;
      ushort4 r;
      r.x = f2b(t[j][i4 + 0]); r.y = f2b(t[j][i4 + 1]);
      r.z = f2b(t[j][i4 + 2]); r.w = f2b(t[j][i4 + 3]);
      *(ushort4*)(dst + (size_t)(j0 + j) * NN + (i0 + i4)) = r;
    }
  } else {
    int i0 = (x - 1024) * 64;
    int lane = tid & 63, w = tid >> 6;
    int q = lane >> 4, m = lane & 15;
    f32x4 acc[8];
#pragma unroll
    for (int t = 0; t < 8; ++t)
#pragma unroll
      for (int r = 0; r < 4; ++r) acc[t][r] = 0.f;
    int irow = i0 + w * 16 + m;
    const float* hrow = X + ((size_t)b * NN + irow) * DD;
#pragma unroll
    for (int kk = 0; kk < 4; ++kk) {
      int d0 = kk * 32 + q * 8;
      float4 h0 = *(const float4*)(hrow + d0);
      float4 h1 = *(const float4*)(hrow + d0 + 4);
      union { bf16x8 v; unsigned short s[8]; } ub;
      ub.s[0] = f2b(h0.x); ub.s[1] = f2b(h0.y); ub.s[2] = f2b(h0.z); ub.s[3] = f2b(h0.w);
      ub.s[4] = f2b(h1.x); ub.s[5] = f2b(h1.y); ub.s[6] = f2b(h1.z); ub.s[7] = f2b(h1.w);
#pragma unroll
      for (int mt = 0; mt < 8; ++mt) {
        bf16x8 af = *(const bf16x8*)(WT + (mt * 16 + m) * 128 + d0);
        acc[mt] = __builtin_amdgcn_mfma_f32_16x16x32_bf16(af, ub.v, acc[mt], 0, 0, 0);
      }
    }
    unsigned short* dst = hwT + (size_t)b * DD * NN;
#pragma unroll
    for (int mt = 0; mt < 8; ++mt)
#pragma unroll
      for (int r = 0; r < 4; ++r)
        dst[(size_t)(mt * 16 + q * 4 + r) * NN + irow] = f2b(acc[mt][r]);
  }
}

// Fused per-layer: full-K gemm2 (fp32 acc, no pacc) + bias + res + LN + ReLU -> out,
// then (doW) gemm1 h@W -> hwT_out. Tile 64(j)x128(e), 4 waves (32x64 each), K=2048.
// LDS 48KB (2x24KB staging dbuf; epilogue z[64][132] f32 aliases it) -> 2-3 blocks/CU.
// One barrier per K-step: STAGE(next buf) -> compute(cur) -> __syncthreads().
// W fragments for gemm1 read straight from global WT (32KB, L1-resident) like k_pre.
__global__ __launch_bounds__(256) void k_layer(const unsigned short* __restrict__ adjT,
                                               const unsigned short* __restrict__ hwT_in,
                                               const float* __restrict__ res,
                                               const float* __restrict__ bias,
                                               const float* __restrict__ gamma,
                                               const float* __restrict__ beta,
                                               const unsigned short* __restrict__ WTn,
                                               float* __restrict__ outf,
                                               unsigned short* __restrict__ hwT_out,
                                               int doW) {
  __shared__ __align__(16) unsigned char smem[49152];
  int tid = threadIdx.x;
  int lane = tid & 63, w = tid >> 6;
  int q = lane >> 4, m = lane & 15;
  int wj = w & 1, we = w >> 1;
  int b = blockIdx.y, j0 = blockIdx.x * 64;

  const unsigned short* At = adjT + (size_t)b * NN * NN;
  const unsigned short* Ht = hwT_in + (size_t)b * DD * NN;

  // pre-swizzled global sources (same involution as the LDS read: cg = c ^ (r&7))
  const unsigned short* aSrc[2];
  const unsigned short* hSrc[4];
#pragma unroll
  for (int it = 0; it < 2; ++it) {
    int p = (w * 2 + it) * 64 + lane;
    int r = p >> 3, cg = (p & 7) ^ (r & 7);
    aSrc[it] = At + (size_t)(j0 + r) * NN + cg * 8;
  }
#pragma unroll
  for (int it = 0; it < 4; ++it) {
    int p = (w * 4 + it) * 64 + lane;
    int r = p >> 3, cg = (p & 7) ^ (r & 7);
    hSrc[it] = Ht + (size_t)r * NN + cg * 8;
  }

#define STAGE_K(bufbase)                                                              \
  do {                                                                                \
    _Pragma("unroll") for (int it = 0; it < 2; ++it) {                                \
      __builtin_amdgcn_global_load_lds((glob_u32*)aSrc[it],                           \
          (lds_u32*)((bufbase) + (w * 2 + it) * 1024 + lane * 16), 16, 0, 0);         \
      aSrc[it] += 64;                                                                 \
    }                                                                                 \
    _Pragma("unroll") for (int it = 0; it < 4; ++it) {                                \
      __builtin_amdgcn_global_load_lds((glob_u32*)hSrc[it],                           \
          (lds_u32*)((bufbase) + 8192 + (w * 4 + it) * 1024 + lane * 16), 16, 0, 0);  \
      hSrc[it] += 64;                                                                 \
    }                                                                                 \
  } while (0)

  f32x4 acc[2][4];
#pragma unroll
  for (int mt = 0; mt < 2; ++mt)
#pragma unroll
    for (int nt = 0; nt < 4; ++nt)
#pragma unroll
      for (int r = 0; r < 4; ++r) acc[mt][nt][r] = 0.f;

  STAGE_K(smem);
  __syncthreads();
  int cur = 0;
  for (int t = 0; t < 32; ++t) {
    if (t < 31) STAGE_K(smem + (cur ^ 1) * 24576);
    const unsigned short* sA = (const unsigned short*)(smem + cur * 24576);
    const unsigned short* sH = sA + 4096;
#pragma unroll
    for (int kk = 0; kk < 2; ++kk) {
      bf16x8 af[2], bv[4];
#pragma unroll
      for (int mt = 0; mt < 2; ++mt) {
        int r = wj * 32 + mt * 16 + m;
        int c = (kk * 4 + q) ^ (r & 7);
        af[mt] = *(const bf16x8*)(sA + r * 64 + c * 8);
      }
#pragma unroll
      for (int nt = 0; nt < 4; ++nt) {
        int r = we * 64 + nt * 16 + m;
        int c = (kk * 4 + q) ^ (r & 7);
        bv[nt] = *(const bf16x8*)(sH + r * 64 + c * 8);
      }
#pragma unroll
      for (int mt = 0; mt < 2; ++mt)
#pragma unroll
        for (int nt = 0; nt < 4; ++nt)
          acc[mt][nt] = __builtin_amdgcn_mfma_f32_16x16x32_bf16(af[mt], bv[nt], acc[mt][nt], 0, 0, 0);
    }
    __syncthreads();
    cur ^= 1;
  }
#undef STAGE_K

  // Epilogue: staging buffers are dead; alias z[64][132] f32 + smu/srs over them.
  float* z = (float*)smem;                       // 33792 B
  float* smu = (float*)(smem + 33792);           // 256 B
  float* srs = (float*)(smem + 34048);           // 256 B

  // 1) acc -> z (scalar stores; 2-way bank alias max, free)
#pragma unroll
  for (int mt = 0; mt < 2; ++mt)
#pragma unroll
    for (int nt = 0; nt < 4; ++nt)
#pragma unroll
      for (int r = 0; r < 4; ++r) {
        int row = wj * 32 + mt * 16 + q * 4 + r;
        int col = we * 64 + nt * 16 + m;
        z[row * 132 + col] = acc[mt][nt][r];
      }
  __syncthreads();

  // 2) z += bias + res  (coalesced global reads)
  size_t base = ((size_t)b * NN + j0) * DD;
#pragma unroll
  for (int p = 0; p < 4; ++p) {
    int idx = p * 256 + tid;
    int j = idx >> 4, c8 = (idx & 15) * 8;
    const float4* r4 = (const float4*)(res + base + (size_t)j * DD + c8);
    float4 r0 = r4[0], r1 = r4[1];
    const float4* bi4 = (const float4*)(bias + c8);
    float4 b0 = bi4[0], b1 = bi4[1];
    float* zp = z + j * 132 + c8;
    zp[0] += r0.x + b0.x; zp[1] += r0.y + b0.y; zp[2] += r0.z + b0.z; zp[3] += r0.w + b0.w;
    zp[4] += r1.x + b1.x; zp[5] += r1.y + b1.y; zp[6] += r1.z + b1.z; zp[7] += r1.w + b1.w;
  }
  __syncthreads();

  // 3) LN stats: 4 threads/row, interleaved (2-way max)
  {
    int j = tid >> 2, s = tid & 3;
    float sum = 0.f, sq = 0.f;
#pragma unroll
    for (int k = 0; k < 32; ++k) {
      float v = z[j * 132 + s + 4 * k];
      sum += v; sq += v * v;
    }
    sum += __shfl_xor(sum, 1); sq += __shfl_xor(sq, 1);
    sum += __shfl_xor(sum, 2); sq += __shfl_xor(sq, 2);
    if (s == 0) {
      float mu = sum * (1.f / 128.f);
      float var = sq * (1.f / 128.f) - mu * mu;
      smu[j] = mu;
      srs[j] = rsqrtf(var + 1e-5f);
    }
  }
  __syncthreads();

  // 4) normalize + ReLU -> out (coalesced) and back into z for gemm1
  {
    int e = tid & 127;
    float g = gamma[e], bt = beta[e];
#pragma unroll
    for (int p = 0; p < 32; ++p) {
      int idx = p * 256 + tid;
      int j = idx >> 7;
      float v = (z[j * 132 + e] - smu[j]) * srs[j] * g + bt;
      v = fmaxf(v, 0.f);
      outf[base + idx] = v;
      z[j * 132 + e] = v;   // same thread, same slot: no race
    }
  }
  if (!doW) return;
  __syncthreads();

  // 5) gemm1: hwT_out[e'][j0+row] = (h @ Wn)^T ; W frags from global (L1-resident 32KB)
  f32x4 a2[8];
#pragma unroll
  for (int t = 0; t < 8; ++t)
#pragma unroll
    for (int r = 0; r < 4; ++r) a2[t][r] = 0.f;
  const float* hrow = z + (w * 16 + m) * 132;
#pragma unroll
  for (int kk = 0; kk < 4; ++kk) {
    int d0 = kk * 32 + q * 8;
    float4 h0 = *(const float4*)(hrow + d0);
    float4 h1 = *(const float4*)(hrow + d0 + 4);
    union { bf16x8 v; unsigned short s[8]; } ub;
    ub.s[0] = f2b(h0.x); ub.s[1] = f2b(h0.y); ub.s[2] = f2b(h0.z); ub.s[3] = f2b(h0.w);
    ub.s[4] = f2b(h1.x); ub.s[5] = f2b(h1.y); ub.s[6] = f2b(h1.z); ub.s[7] = f2b(h1.w);
#pragma unroll
    for (int mt = 0; mt < 8; ++mt) {
      bf16x8 af = *(const bf16x8*)(WTn + (mt * 16 + m) * 128 + d0);
      a2[mt] = __builtin_amdgcn_mfma_f32_16x16x32_bf16(af, ub.v, a2[mt], 0, 0, 0);
    }
  }
  unsigned short* dst = hwT_out + (size_t)b * DD * NN;
  int irow = j0 + w * 16 + m;
#pragma unroll
  for (int mt = 0; mt < 8; ++mt)
#pragma unroll
    for (int r = 0; r < 4; ++r)
      dst[(size_t)(mt * 16 + q * 4 + r) * NN + irow] = f2b(a2[mt][r]);
}

extern "C" void kernel_launch(void* const* d_in, const int* in_sizes, int n_in,
                              void* d_out, int out_size, void* d_ws, size_t ws_size,
                              hipStream_t stream) {
  const float* X   = (const float*)d_in[0];
  const float* adj = (const float*)d_in[1];
  const float* Ws  = (const float*)d_in[2];
  const float* bs  = (const float*)d_in[3];
  const float* gms = (const float*)d_in[4];
  const float* bts = (const float*)d_in[5];
  float* out = (float*)d_out;

  // ws: adjT bf16 (134MB) | hwT_A (8.4MB) | hwT_B (8.4MB) | WT bf16 (96KB)
  unsigned short* adjT = (unsigned short*)d_ws;
  unsigned short* hwTA = adjT + (size_t)BB * NN * NN;
  unsigned short* hwTB = hwTA + (size_t)BB * DD * NN;
  unsigned short* WT   = hwTB + (size_t)BB * DD * NN;

  k_wt<<<dim3(2, 2, 3), 256, 0, stream>>>(Ws, WT);
  k_pre<<<dim3(1056, BB), 256, 0, stream>>>(adj, adjT, X, WT, hwTA);
  unsigned short* hin = hwTA;
  unsigned short* hout = hwTB;
  for (int l = 0; l < 3; ++l) {
    const float* res = (l == 0) ? X : (const float*)out;
    const unsigned short* WTn = WT + (size_t)((l < 2) ? (l + 1) : 0) * DD * DD;
    k_layer<<<dim3(NN / 64, BB), 256, 0, stream>>>(adjT, hin, res, bs + l * DD,
                                                   gms + l * DD, bts + l * DD,
                                                   WTn, out, hout, (l < 2) ? 1 : 0);
    unsigned short* tmp = hin; hin = hout; hout = tmp;
  }
}

// Round 2
// 206.004 us; speedup vs baseline: 1.1832x; 1.0580x over previous
//
#include <hip/hip_runtime.h>

#define BB 16
#define NN 2048
#define DD 128

typedef __attribute__((ext_vector_type(8))) __bf16 bf16x8;
typedef __attribute__((ext_vector_type(4))) float f32x4;
typedef __attribute__((ext_vector_type(4))) unsigned int u32x4;
typedef __attribute__((address_space(3))) unsigned int lds_u32;
typedef __attribute__((address_space(1))) const unsigned int glob_u32;

static __device__ __forceinline__ unsigned short f2b(float f) {
  union { float f; unsigned int u; } c; c.f = f;
  unsigned int u = c.u;
  unsigned int r = (u + 0x7FFFu + ((u >> 16) & 1u)) >> 16;
  return (unsigned short)r;
}

// WT[l][e][d] = bf16(W[l][d][e])  -- 96 KB total, L2-resident afterwards
__global__ void k_wt(const float* __restrict__ W, unsigned short* __restrict__ WT) {
  __shared__ float t[64][65];
  int l = blockIdx.z, d0 = blockIdx.x * 64, e0 = blockIdx.y * 64;
  int tid = threadIdx.x;
  const float* src = W + (size_t)l * DD * DD;
  for (int p = 0; p < 16; ++p) {
    int idx = p * 256 + tid;
    int d = idx >> 6, e = idx & 63;
    t[e][d] = src[(size_t)(d0 + d) * DD + (e0 + e)];
  }
  __syncthreads();
  unsigned short* dst = WT + (size_t)l * DD * DD;
  for (int p = 0; p < 4; ++p) {
    int idx = p * 256 + tid;
    int e = idx >> 4, d4 = (idx & 15) * 4;
    ushort4 r;
    r.x = f2b(t[e][d4 + 0]); r.y = f2b(t[e][d4 + 1]);
    r.z = f2b(t[e][d4 + 2]); r.w = f2b(t[e][d4 + 3]);
    *(ushort4*)(dst + (size_t)(e0 + e) * DD + (d0 + d4)) = r;
  }
}

// Merged: x<1024 -> adj transpose tile; x>=1024 -> layer-0 gemm1 (X fp32, WT global frags)
__global__ __launch_bounds__(256) void k_pre(const float* __restrict__ adj,
                                             unsigned short* __restrict__ adjT,
                                             const float* __restrict__ X,
                                             const unsigned short* __restrict__ WT,
                                             unsigned short* __restrict__ hwT) {
  int b = blockIdx.y, x = blockIdx.x, tid = threadIdx.x;
  if (x < 1024) {
    __shared__ float t[64][65];
    int j0 = (x >> 5) * 64, i0 = (x & 31) * 64;
    const float* src = adj + (size_t)b * NN * NN;
    for (int p = 0; p < 16; ++p) {
      int idx = p * 256 + tid;
      int i = idx >> 6, j = idx & 63;
      t[j][i] = src[(size_t)(i0 + i) * NN + (j0 + j)];
    }
    __syncthreads();
    unsigned short* dst = adjT + (size_t)b * NN * NN;
    for (int p = 0; p < 4; ++p) {
      int idx = p * 256 + tid;
      int j = idx >> 4, i4 = (idx & 15) * 4;
      ushort4 r;
      r.x = f2b(t[j][i4 + 0]); r.y = f2b(t[j][i4 + 1]);
      r.z = f2b(t[j][i4 + 2]); r.w = f2b(t[j][i4 + 3]);
      *(ushort4*)(dst + (size_t)(j0 + j) * NN + (i0 + i4)) = r;
    }
  } else {
    int i0 = (x - 1024) * 64;
    int lane = tid & 63, w = tid >> 6;
    int q = lane >> 4, m = lane & 15;
    f32x4 acc[8];
#pragma unroll
    for (int t = 0; t < 8; ++t)
#pragma unroll
      for (int r = 0; r < 4; ++r) acc[t][r] = 0.f;
    int irow = i0 + w * 16 + m;
    const float* hrow = X + ((size_t)b * NN + irow) * DD;
#pragma unroll
    for (int kk = 0; kk < 4; ++kk) {
      int d0 = kk * 32 + q * 8;
      float4 h0 = *(const float4*)(hrow + d0);
      float4 h1 = *(const float4*)(hrow + d0 + 4);
      union { bf16x8 v; unsigned short s[8]; } ub;
      ub.s[0] = f2b(h0.x); ub.s[1] = f2b(h0.y); ub.s[2] = f2b(h0.z); ub.s[3] = f2b(h0.w);
      ub.s[4] = f2b(h1.x); ub.s[5] = f2b(h1.y); ub.s[6] = f2b(h1.z); ub.s[7] = f2b(h1.w);
#pragma unroll
      for (int mt = 0; mt < 8; ++mt) {
        bf16x8 af = *(const bf16x8*)(WT + (mt * 16 + m) * 128 + d0);
        acc[mt] = __builtin_amdgcn_mfma_f32_16x16x32_bf16(af, ub.v, acc[mt], 0, 0, 0);
      }
    }
    unsigned short* dst = hwT + (size_t)b * DD * NN;
#pragma unroll
    for (int mt = 0; mt < 8; ++mt)
#pragma unroll
      for (int r = 0; r < 4; ++r)
        dst[(size_t)(mt * 16 + q * 4 + r) * NN + irow] = f2b(acc[mt][r]);
  }
}

// Fused per-layer: full-K gemm2 (fp32 acc) + bias + res + LN + ReLU -> out,
// then (doW) gemm1 h@W -> hwT_out. Tile 64(j)x128(e), 4 waves (32x64 each), K=2048.
// T3/T4: triple-buffered staging (3x24KB=72KB), raw s_barrier + counted vmcnt(6)
// per K-step -- the global_load_lds queue is never drained to 0 in the main loop.
// Stage t+2 issued AFTER the barrier (buffer (t+2)%3 was last read at t-1; crossing
// barrier(t) implies those ds_reads retired). Epilogue z[64][132] aliases staging.
__global__ __launch_bounds__(256) void k_layer(const unsigned short* __restrict__ adjT,
                                               const unsigned short* __restrict__ hwT_in,
                                               const float* __restrict__ res,
                                               const float* __restrict__ bias,
                                               const float* __restrict__ gamma,
                                               const float* __restrict__ beta,
                                               const unsigned short* __restrict__ WTn,
                                               float* __restrict__ outf,
                                               unsigned short* __restrict__ hwT_out,
                                               int doW) {
  __shared__ __align__(16) unsigned char smem[73728];  // 3 x 24576
  int tid = threadIdx.x;
  int lane = tid & 63, w = tid >> 6;
  int q = lane >> 4, m = lane & 15;
  int wj = w & 1, we = w >> 1;

  // XCD-chunked decode: all 32 j-tiles of a batch land on one XCD -> hwT_in
  // (512 KB/batch) stays L2-resident. XCD = lin%8 (dispatch round-robin).
  int lin = blockIdx.x;
  int xcd = lin & 7, slot = lin >> 3;
  int b = xcd * 2 + (slot >> 5);
  int j0 = (slot & 31) * 64;

  const unsigned short* At = adjT + (size_t)b * NN * NN;
  const unsigned short* Ht = hwT_in + (size_t)b * DD * NN;

  // pre-swizzled global sources (same involution as the LDS read: cg = c ^ (r&7))
  const unsigned short* aSrc[2];
  const unsigned short* hSrc[4];
#pragma unroll
  for (int it = 0; it < 2; ++it) {
    int p = (w * 2 + it) * 64 + lane;
    int r = p >> 3, cg = (p & 7) ^ (r & 7);
    aSrc[it] = At + (size_t)(j0 + r) * NN + cg * 8;
  }
#pragma unroll
  for (int it = 0; it < 4; ++it) {
    int p = (w * 4 + it) * 64 + lane;
    int r = p >> 3, cg = (p & 7) ^ (r & 7);
    hSrc[it] = Ht + (size_t)r * NN + cg * 8;
  }

#define STAGE_K(bufbase)                                                              \
  do {                                                                                \
    _Pragma("unroll") for (int it = 0; it < 2; ++it) {                                \
      __builtin_amdgcn_global_load_lds((glob_u32*)aSrc[it],                           \
          (lds_u32*)((bufbase) + (w * 2 + it) * 1024 + lane * 16), 16, 0, 0);         \
      aSrc[it] += 64;                                                                 \
    }                                                                                 \
    _Pragma("unroll") for (int it = 0; it < 4; ++it) {                                \
      __builtin_amdgcn_global_load_lds((glob_u32*)hSrc[it],                           \
          (lds_u32*)((bufbase) + 8192 + (w * 4 + it) * 1024 + lane * 16), 16, 0, 0);  \
      hSrc[it] += 64;                                                                 \
    }                                                                                 \
  } while (0)

  f32x4 acc[2][4];
#pragma unroll
  for (int mt = 0; mt < 2; ++mt)
#pragma unroll
    for (int nt = 0; nt < 4; ++nt)
#pragma unroll
      for (int r = 0; r < 4; ++r) acc[mt][nt][r] = 0.f;

  STAGE_K(smem);            // t=0   (6 loads in flight)
  STAGE_K(smem + 24576);    // t=1   (12 in flight)
  int rb = 0;
  for (int t = 0; t < 32; ++t) {
    // own previous-stage loads done; barrier makes ALL waves' loads visible
    if (t < 31) { asm volatile("s_waitcnt vmcnt(6)" ::: "memory"); }
    else        { asm volatile("s_waitcnt vmcnt(0)" ::: "memory"); }
    __builtin_amdgcn_sched_barrier(0);
    __builtin_amdgcn_s_barrier();
    __builtin_amdgcn_sched_barrier(0);
    if (t < 30) {
      int sb = rb + 2; if (sb >= 3) sb -= 3;
      STAGE_K(smem + sb * 24576);
    }
    const unsigned short* sA = (const unsigned short*)(smem + rb * 24576);
    const unsigned short* sH = sA + 4096;  // +8192 bytes
#pragma unroll
    for (int kk = 0; kk < 2; ++kk) {
      bf16x8 af[2], bv[4];
#pragma unroll
      for (int mt = 0; mt < 2; ++mt) {
        int r = wj * 32 + mt * 16 + m;
        int c = (kk * 4 + q) ^ (r & 7);
        af[mt] = *(const bf16x8*)(sA + r * 64 + c * 8);
      }
#pragma unroll
      for (int nt = 0; nt < 4; ++nt) {
        int r = we * 64 + nt * 16 + m;
        int c = (kk * 4 + q) ^ (r & 7);
        bv[nt] = *(const bf16x8*)(sH + r * 64 + c * 8);
      }
#pragma unroll
      for (int mt = 0; mt < 2; ++mt)
#pragma unroll
        for (int nt = 0; nt < 4; ++nt)
          acc[mt][nt] = __builtin_amdgcn_mfma_f32_16x16x32_bf16(af[mt], bv[nt], acc[mt][nt], 0, 0, 0);
    }
    rb = rb + 1; if (rb == 3) rb = 0;
  }
#undef STAGE_K
  __syncthreads();  // staging reads (t=31 uses buf1) must retire before z-alias writes

  // Epilogue: staging buffers dead; alias z[64][132] f32 + smu/srs over them.
  float* z = (float*)smem;                       // 33792 B
  float* smu = (float*)(smem + 33792);           // 256 B
  float* srs = (float*)(smem + 34048);           // 256 B

  // 1) acc -> z
#pragma unroll
  for (int mt = 0; mt < 2; ++mt)
#pragma unroll
    for (int nt = 0; nt < 4; ++nt)
#pragma unroll
      for (int r = 0; r < 4; ++r) {
        int row = wj * 32 + mt * 16 + q * 4 + r;
        int col = we * 64 + nt * 16 + m;
        z[row * 132 + col] = acc[mt][nt][r];
      }
  __syncthreads();

  // 2) z += bias + res  (coalesced global reads)
  size_t base = ((size_t)b * NN + j0) * DD;
#pragma unroll
  for (int p = 0; p < 4; ++p) {
    int idx = p * 256 + tid;
    int j = idx >> 4, c8 = (idx & 15) * 8;
    const float4* r4 = (const float4*)(res + base + (size_t)j * DD + c8);
    float4 r0 = r4[0], r1 = r4[1];
    const float4* bi4 = (const float4*)(bias + c8);
    float4 b0 = bi4[0], b1 = bi4[1];
    float* zp = z + j * 132 + c8;
    zp[0] += r0.x + b0.x; zp[1] += r0.y + b0.y; zp[2] += r0.z + b0.z; zp[3] += r0.w + b0.w;
    zp[4] += r1.x + b1.x; zp[5] += r1.y + b1.y; zp[6] += r1.z + b1.z; zp[7] += r1.w + b1.w;
  }
  __syncthreads();

  // 3) LN stats: 4 threads/row, interleaved (2-way max)
  {
    int j = tid >> 2, s = tid & 3;
    float sum = 0.f, sq = 0.f;
#pragma unroll
    for (int k = 0; k < 32; ++k) {
      float v = z[j * 132 + s + 4 * k];
      sum += v; sq += v * v;
    }
    sum += __shfl_xor(sum, 1); sq += __shfl_xor(sq, 1);
    sum += __shfl_xor(sum, 2); sq += __shfl_xor(sq, 2);
    if (s == 0) {
      float mu = sum * (1.f / 128.f);
      float var = sq * (1.f / 128.f) - mu * mu;
      smu[j] = mu;
      srs[j] = rsqrtf(var + 1e-5f);
    }
  }
  __syncthreads();

  // 4) normalize + ReLU -> out (coalesced) and back into z for gemm1
  {
    int e = tid & 127;
    float g = gamma[e], bt = beta[e];
#pragma unroll
    for (int p = 0; p < 32; ++p) {
      int idx = p * 256 + tid;
      int j = idx >> 7;
      float v = (z[j * 132 + e] - smu[j]) * srs[j] * g + bt;
      v = fmaxf(v, 0.f);
      outf[base + idx] = v;
      z[j * 132 + e] = v;   // same thread, same slot: no race
    }
  }
  if (!doW) return;
  __syncthreads();

  // 5) gemm1: hwT_out[e'][j0+row] = (h @ Wn)^T ; W frags from global (L2-resident 32KB)
  f32x4 a2[8];
#pragma unroll
  for (int t = 0; t < 8; ++t)
#pragma unroll
    for (int r = 0; r < 4; ++r) a2[t][r] = 0.f;
  const float* hrow = z + (w * 16 + m) * 132;
#pragma unroll
  for (int kk = 0; kk < 4; ++kk) {
    int d0 = kk * 32 + q * 8;
    float4 h0 = *(const float4*)(hrow + d0);
    float4 h1 = *(const float4*)(hrow + d0 + 4);
    union { bf16x8 v; unsigned short s[8]; } ub;
    ub.s[0] = f2b(h0.x); ub.s[1] = f2b(h0.y); ub.s[2] = f2b(h0.z); ub.s[3] = f2b(h0.w);
    ub.s[4] = f2b(h1.x); ub.s[5] = f2b(h1.y); ub.s[6] = f2b(h1.z); ub.s[7] = f2b(h1.w);
#pragma unroll
    for (int mt = 0; mt < 8; ++mt) {
      bf16x8 af = *(const bf16x8*)(WTn + (mt * 16 + m) * 128 + d0);
      a2[mt] = __builtin_amdgcn_mfma_f32_16x16x32_bf16(af, ub.v, a2[mt], 0, 0, 0);
    }
  }
  unsigned short* dst = hwT_out + (size_t)b * DD * NN;
  int irow = j0 + w * 16 + m;
#pragma unroll
  for (int mt = 0; mt < 8; ++mt)
#pragma unroll
    for (int r = 0; r < 4; ++r)
      dst[(size_t)(mt * 16 + q * 4 + r) * NN + irow] = f2b(a2[mt][r]);
}

extern "C" void kernel_launch(void* const* d_in, const int* in_sizes, int n_in,
                              void* d_out, int out_size, void* d_ws, size_t ws_size,
                              hipStream_t stream) {
  const float* X   = (const float*)d_in[0];
  const float* adj = (const float*)d_in[1];
  const float* Ws  = (const float*)d_in[2];
  const float* bs  = (const float*)d_in[3];
  const float* gms = (const float*)d_in[4];
  const float* bts = (const float*)d_in[5];
  float* out = (float*)d_out;

  // ws: adjT bf16 (134MB) | hwT_A (8.4MB) | hwT_B (8.4MB) | WT bf16 (96KB)
  unsigned short* adjT = (unsigned short*)d_ws;
  unsigned short* hwTA = adjT + (size_t)BB * NN * NN;
  unsigned short* hwTB = hwTA + (size_t)BB * DD * NN;
  unsigned short* WT   = hwTB + (size_t)BB * DD * NN;

  k_wt<<<dim3(2, 2, 3), 256, 0, stream>>>(Ws, WT);
  k_pre<<<dim3(1056, BB), 256, 0, stream>>>(adj, adjT, X, WT, hwTA);
  unsigned short* hin = hwTA;
  unsigned short* hout = hwTB;
  for (int l = 0; l < 3; ++l) {
    const float* res = (l == 0) ? X : (const float*)out;
    const unsigned short* WTn = WT + (size_t)((l < 2) ? (l + 1) : 0) * DD * DD;
    k_layer<<<dim3(512), 256, 0, stream>>>(adjT, hin, res, bs + l * DD,
                                           gms + l * DD, bts + l * DD,
                                           WTn, out, hout, (l < 2) ? 1 : 0);
    unsigned short* tmp = hin; hin = hout; hout = tmp;
  }
}

// Round 3
// 202.963 us; speedup vs baseline: 1.2009x; 1.0150x over previous
//
#include <hip/hip_runtime.h>

#define BB 16
#define NN 2048
#define DD 128

typedef __attribute__((ext_vector_type(8))) __bf16 bf16x8;
typedef __attribute__((ext_vector_type(4))) float f32x4;
typedef __attribute__((ext_vector_type(4))) unsigned int u32x4;
typedef __attribute__((address_space(3))) unsigned int lds_u32;
typedef __attribute__((address_space(1))) const unsigned int glob_u32;

static __device__ __forceinline__ unsigned short f2b(float f) {
  union { float f; unsigned int u; } c; c.f = f;
  unsigned int u = c.u;
  unsigned int r = (u + 0x7FFFu + ((u >> 16) & 1u)) >> 16;
  return (unsigned short)r;
}

// WT[l][e][d] = bf16(W[l][d][e])  -- 96 KB total, L2-resident afterwards
__global__ void k_wt(const float* __restrict__ W, unsigned short* __restrict__ WT) {
  __shared__ float t[64][65];
  int l = blockIdx.z, d0 = blockIdx.x * 64, e0 = blockIdx.y * 64;
  int tid = threadIdx.x;
  const float* src = W + (size_t)l * DD * DD;
  for (int p = 0; p < 16; ++p) {
    int idx = p * 256 + tid;
    int d = idx >> 6, e = idx & 63;
    t[e][d] = src[(size_t)(d0 + d) * DD + (e0 + e)];
  }
  __syncthreads();
  unsigned short* dst = WT + (size_t)l * DD * DD;
  for (int p = 0; p < 4; ++p) {
    int idx = p * 256 + tid;
    int e = idx >> 4, d4 = (idx & 15) * 4;
    ushort4 r;
    r.x = f2b(t[e][d4 + 0]); r.y = f2b(t[e][d4 + 1]);
    r.z = f2b(t[e][d4 + 2]); r.w = f2b(t[e][d4 + 3]);
    *(ushort4*)(dst + (size_t)(e0 + e) * DD + (d0 + d4)) = r;
  }
}

// Merged: x<1024 -> adj transpose tile; x>=1024 -> layer-0 gemm1 (X fp32, WT global frags)
__global__ __launch_bounds__(256) void k_pre(const float* __restrict__ adj,
                                             unsigned short* __restrict__ adjT,
                                             const float* __restrict__ X,
                                             const unsigned short* __restrict__ WT,
                                             unsigned short* __restrict__ hwT) {
  int b = blockIdx.y, x = blockIdx.x, tid = threadIdx.x;
  if (x < 1024) {
    __shared__ float t[64][65];
    int j0 = (x >> 5) * 64, i0 = (x & 31) * 64;
    const float* src = adj + (size_t)b * NN * NN;
    for (int p = 0; p < 16; ++p) {
      int idx = p * 256 + tid;
      int i = idx >> 6, j = idx & 63;
      t[j][i] = src[(size_t)(i0 + i) * NN + (j0 + j)];
    }
    __syncthreads();
    unsigned short* dst = adjT + (size_t)b * NN * NN;
    for (int p = 0; p < 4; ++p) {
      int idx = p * 256 + tid;
      int j = idx >> 4, i4 = (idx & 15) * 4;
      ushort4 r;
      r.x = f2b(t[j][i4 + 0]); r.y = f2b(t[j][i4 + 1]);
      r.z = f2b(t[j][i4 + 2]); r.w = f2b(t[j][i4 + 3]);
      *(ushort4*)(dst + (size_t)(j0 + j) * NN + (i0 + i4)) = r;
    }
  } else {
    int i0 = (x - 1024) * 64;
    int lane = tid & 63, w = tid >> 6;
    int q = lane >> 4, m = lane & 15;
    f32x4 acc[8];
#pragma unroll
    for (int t = 0; t < 8; ++t)
#pragma unroll
      for (int r = 0; r < 4; ++r) acc[t][r] = 0.f;
    int irow = i0 + w * 16 + m;
    const float* hrow = X + ((size_t)b * NN + irow) * DD;
#pragma unroll
    for (int kk = 0; kk < 4; ++kk) {
      int d0 = kk * 32 + q * 8;
      float4 h0 = *(const float4*)(hrow + d0);
      float4 h1 = *(const float4*)(hrow + d0 + 4);
      union { bf16x8 v; unsigned short s[8]; } ub;
      ub.s[0] = f2b(h0.x); ub.s[1] = f2b(h0.y); ub.s[2] = f2b(h0.z); ub.s[3] = f2b(h0.w);
      ub.s[4] = f2b(h1.x); ub.s[5] = f2b(h1.y); ub.s[6] = f2b(h1.z); ub.s[7] = f2b(h1.w);
#pragma unroll
      for (int mt = 0; mt < 8; ++mt) {
        bf16x8 af = *(const bf16x8*)(WT + (mt * 16 + m) * 128 + d0);
        acc[mt] = __builtin_amdgcn_mfma_f32_16x16x32_bf16(af, ub.v, acc[mt], 0, 0, 0);
      }
    }
    unsigned short* dst = hwT + (size_t)b * DD * NN;
#pragma unroll
    for (int mt = 0; mt < 8; ++mt)
#pragma unroll
      for (int r = 0; r < 4; ++r)
        dst[(size_t)(mt * 16 + q * 4 + r) * NN + irow] = f2b(acc[mt][r]);
  }
}

// Fused per-layer, tile 128(j)x128(e), 512 threads / 8 waves (wave-tile 32x64), K=2048.
// Per K-step stages A 16KB + H 16KB = 32KB (was 48KB/CU with 2x64-row blocks).
// Triple-buffered (3x32KB = 96KB LDS, 1 block/CU), raw s_barrier + counted vmcnt(4):
// the global_load_lds queue is never drained to 0 in the main loop (T4).
// Epilogue z[128][132] f32 (66KB) aliases the dead staging buffers.
__global__ __launch_bounds__(512) void k_layer(const unsigned short* __restrict__ adjT,
                                               const unsigned short* __restrict__ hwT_in,
                                               const float* __restrict__ res,
                                               const float* __restrict__ bias,
                                               const float* __restrict__ gamma,
                                               const float* __restrict__ beta,
                                               const unsigned short* __restrict__ WTn,
                                               float* __restrict__ outf,
                                               unsigned short* __restrict__ hwT_out,
                                               int doW) {
  __shared__ __align__(16) unsigned char smem[98304];  // 3 x 32768
  int tid = threadIdx.x;
  int lane = tid & 63, w = tid >> 6;          // w in 0..7
  int q = lane >> 4, m = lane & 15;
  int wj = w >> 1, we = w & 1;                // 4 x 2 wave grid -> 32x64 wave tile

  // XCD-chunked decode: 32 blocks/XCD = 2 batches' j-tiles -> hwT_in (1MB) L2-resident.
  int lin = blockIdx.x;
  int xcd = lin & 7, slot = lin >> 3;         // slot 0..31
  int b = xcd * 2 + (slot >> 4);
  int j0 = (slot & 15) * 128;

  const unsigned short* At = adjT + (size_t)b * NN * NN;
  const unsigned short* Ht = hwT_in + (size_t)b * DD * NN;

  // pre-swizzled global sources (same involution as the LDS read: cg = c ^ (r&7))
  const unsigned short* aSrc[2];
  const unsigned short* hSrc[2];
#pragma unroll
  for (int it = 0; it < 2; ++it) {
    int p = (w * 2 + it) * 64 + lane;         // chunk 0..1023 = 128 rows x 8 chunks
    int r = p >> 3, cg = (p & 7) ^ (r & 7);
    aSrc[it] = At + (size_t)(j0 + r) * NN + cg * 8;
    hSrc[it] = Ht + (size_t)r * NN + cg * 8;
  }

#define STAGE_K(bufbase)                                                              \
  do {                                                                                \
    _Pragma("unroll") for (int it = 0; it < 2; ++it) {                                \
      __builtin_amdgcn_global_load_lds((glob_u32*)aSrc[it],                           \
          (lds_u32*)((bufbase) + (w * 2 + it) * 1024 + lane * 16), 16, 0, 0);         \
      aSrc[it] += 64;                                                                 \
    }                                                                                 \
    _Pragma("unroll") for (int it = 0; it < 2; ++it) {                                \
      __builtin_amdgcn_global_load_lds((glob_u32*)hSrc[it],                           \
          (lds_u32*)((bufbase) + 16384 + (w * 2 + it) * 1024 + lane * 16), 16, 0, 0); \
      hSrc[it] += 64;                                                                 \
    }                                                                                 \
  } while (0)

  f32x4 acc[2][4];
#pragma unroll
  for (int mt = 0; mt < 2; ++mt)
#pragma unroll
    for (int nt = 0; nt < 4; ++nt)
#pragma unroll
      for (int r = 0; r < 4; ++r) acc[mt][nt][r] = 0.f;

  STAGE_K(smem);            // t=0   (4 loads in flight)
  STAGE_K(smem + 32768);    // t=1   (8 in flight)
  int rb = 0;
  for (int t = 0; t < 32; ++t) {
    // own previous-stage loads done; barrier makes ALL waves' loads visible
    if (t < 31) { asm volatile("s_waitcnt vmcnt(4)" ::: "memory"); }
    else        { asm volatile("s_waitcnt vmcnt(0)" ::: "memory"); }
    __builtin_amdgcn_sched_barrier(0);
    __builtin_amdgcn_s_barrier();
    __builtin_amdgcn_sched_barrier(0);
    if (t < 30) {
      int sb = rb + 2; if (sb >= 3) sb -= 3;
      STAGE_K(smem + sb * 32768);
    }
    const unsigned short* sA = (const unsigned short*)(smem + rb * 32768);
    const unsigned short* sH = sA + 8192;  // +16384 bytes
#pragma unroll
    for (int kk = 0; kk < 2; ++kk) {
      bf16x8 af[2], bv[4];
#pragma unroll
      for (int mt = 0; mt < 2; ++mt) {
        int r = wj * 32 + mt * 16 + m;
        int c = (kk * 4 + q) ^ (r & 7);
        af[mt] = *(const bf16x8*)(sA + r * 64 + c * 8);
      }
#pragma unroll
      for (int nt = 0; nt < 4; ++nt) {
        int r = we * 64 + nt * 16 + m;
        int c = (kk * 4 + q) ^ (r & 7);
        bv[nt] = *(const bf16x8*)(sH + r * 64 + c * 8);
      }
#pragma unroll
      for (int mt = 0; mt < 2; ++mt)
#pragma unroll
        for (int nt = 0; nt < 4; ++nt)
          acc[mt][nt] = __builtin_amdgcn_mfma_f32_16x16x32_bf16(af[mt], bv[nt], acc[mt][nt], 0, 0, 0);
    }
    rb = rb + 1; if (rb == 3) rb = 0;
  }
#undef STAGE_K
  __syncthreads();  // t=31 staging reads must retire before z-alias writes

  // Epilogue: staging buffers dead; alias z[128][132] f32 + smu/srs over them.
  float* z = (float*)smem;                       // 67584 B
  float* smu = (float*)(smem + 67584);           // 512 B
  float* srs = (float*)(smem + 68096);           // 512 B

  // 1) acc -> z
#pragma unroll
  for (int mt = 0; mt < 2; ++mt)
#pragma unroll
    for (int nt = 0; nt < 4; ++nt)
#pragma unroll
      for (int r = 0; r < 4; ++r) {
        int row = wj * 32 + mt * 16 + q * 4 + r;
        int col = we * 64 + nt * 16 + m;
        z[row * 132 + col] = acc[mt][nt][r];
      }
  __syncthreads();

  // 2) z += bias + res  (coalesced global reads)
  size_t base = ((size_t)b * NN + j0) * DD;
#pragma unroll
  for (int p = 0; p < 4; ++p) {
    int idx = p * 512 + tid;
    int j = idx >> 4, c8 = (idx & 15) * 8;
    const float4* r4 = (const float4*)(res + base + (size_t)j * DD + c8);
    float4 r0 = r4[0], r1 = r4[1];
    const float4* bi4 = (const float4*)(bias + c8);
    float4 b0 = bi4[0], b1 = bi4[1];
    float* zp = z + j * 132 + c8;
    zp[0] += r0.x + b0.x; zp[1] += r0.y + b0.y; zp[2] += r0.z + b0.z; zp[3] += r0.w + b0.w;
    zp[4] += r1.x + b1.x; zp[5] += r1.y + b1.y; zp[6] += r1.z + b1.z; zp[7] += r1.w + b1.w;
  }
  __syncthreads();

  // 3) LN stats: 4 threads/row, interleaved (2-way max)
  {
    int j = tid >> 2, s = tid & 3;
    float sum = 0.f, sq = 0.f;
#pragma unroll
    for (int k = 0; k < 32; ++k) {
      float v = z[j * 132 + s + 4 * k];
      sum += v; sq += v * v;
    }
    sum += __shfl_xor(sum, 1); sq += __shfl_xor(sq, 1);
    sum += __shfl_xor(sum, 2); sq += __shfl_xor(sq, 2);
    if (s == 0) {
      float mu = sum * (1.f / 128.f);
      float var = sq * (1.f / 128.f) - mu * mu;
      smu[j] = mu;
      srs[j] = rsqrtf(var + 1e-5f);
    }
  }
  __syncthreads();

  // 4) normalize + ReLU -> out (coalesced) and back into z for gemm1
  {
    int e = tid & 127;
    float g = gamma[e], bt = beta[e];
#pragma unroll
    for (int p = 0; p < 32; ++p) {
      int idx = p * 512 + tid;
      int j = idx >> 7;
      float v = (z[j * 132 + e] - smu[j]) * srs[j] * g + bt;
      v = fmaxf(v, 0.f);
      outf[base + idx] = v;
      z[j * 132 + e] = v;   // same thread, same slot: no race
    }
  }
  if (!doW) return;
  __syncthreads();

  // 5) gemm1: hwT_out[e'][j0+row] = (h @ Wn)^T ; 8 waves x 16 rows each.
  f32x4 a2[8];
#pragma unroll
  for (int t = 0; t < 8; ++t)
#pragma unroll
    for (int r = 0; r < 4; ++r) a2[t][r] = 0.f;
  const float* hrow = z + (w * 16 + m) * 132;
#pragma unroll
  for (int kk = 0; kk < 4; ++kk) {
    int d0 = kk * 32 + q * 8;
    float4 h0 = *(const float4*)(hrow + d0);
    float4 h1 = *(const float4*)(hrow + d0 + 4);
    union { bf16x8 v; unsigned short s[8]; } ub;
    ub.s[0] = f2b(h0.x); ub.s[1] = f2b(h0.y); ub.s[2] = f2b(h0.z); ub.s[3] = f2b(h0.w);
    ub.s[4] = f2b(h1.x); ub.s[5] = f2b(h1.y); ub.s[6] = f2b(h1.z); ub.s[7] = f2b(h1.w);
#pragma unroll
    for (int mt = 0; mt < 8; ++mt) {
      bf16x8 af = *(const bf16x8*)(WTn + (mt * 16 + m) * 128 + d0);
      a2[mt] = __builtin_amdgcn_mfma_f32_16x16x32_bf16(af, ub.v, a2[mt], 0, 0, 0);
    }
  }
  unsigned short* dst = hwT_out + (size_t)b * DD * NN;
  int irow = j0 + w * 16 + m;
#pragma unroll
  for (int mt = 0; mt < 8; ++mt)
#pragma unroll
    for (int r = 0; r < 4; ++r)
      dst[(size_t)(mt * 16 + q * 4 + r) * NN + irow] = f2b(a2[mt][r]);
}

extern "C" void kernel_launch(void* const* d_in, const int* in_sizes, int n_in,
                              void* d_out, int out_size, void* d_ws, size_t ws_size,
                              hipStream_t stream) {
  const float* X   = (const float*)d_in[0];
  const float* adj = (const float*)d_in[1];
  const float* Ws  = (const float*)d_in[2];
  const float* bs  = (const float*)d_in[3];
  const float* gms = (const float*)d_in[4];
  const float* bts = (const float*)d_in[5];
  float* out = (float*)d_out;

  // ws: adjT bf16 (134MB) | hwT_A (8.4MB) | hwT_B (8.4MB) | WT bf16 (96KB)
  unsigned short* adjT = (unsigned short*)d_ws;
  unsigned short* hwTA = adjT + (size_t)BB * NN * NN;
  unsigned short* hwTB = hwTA + (size_t)BB * DD * NN;
  unsigned short* WT   = hwTB + (size_t)BB * DD * NN;

  k_wt<<<dim3(2, 2, 3), 256, 0, stream>>>(Ws, WT);
  k_pre<<<dim3(1056, BB), 256, 0, stream>>>(adj, adjT, X, WT, hwTA);
  unsigned short* hin = hwTA;
  unsigned short* hout = hwTB;
  for (int l = 0; l < 3; ++l) {
    const float* res = (l == 0) ? X : (const float*)out;
    const unsigned short* WTn = WT + (size_t)((l < 2) ? (l + 1) : 0) * DD * DD;
    k_layer<<<dim3(256), 512, 0, stream>>>(adjT, hin, res, bs + l * DD,
                                           gms + l * DD, bts + l * DD,
                                           WTn, out, hout, (l < 2) ? 1 : 0);
    unsigned short* tmp = hin; hin = hout; hout = tmp;
  }
}

// Round 5
// 201.347 us; speedup vs baseline: 1.2106x; 1.0080x over previous
//
#include <hip/hip_runtime.h>

#define BB 16
#define NN 2048
#define DD 128

typedef __attribute__((ext_vector_type(8))) __bf16 bf16x8;
typedef __attribute__((ext_vector_type(4))) float f32x4;
typedef __attribute__((ext_vector_type(4))) unsigned int u32x4;
typedef __attribute__((address_space(3))) unsigned int lds_u32;
typedef __attribute__((address_space(1))) const unsigned int glob_u32;

static __device__ __forceinline__ unsigned short f2b(float f) {
  union { float f; unsigned int u; } c; c.f = f;
  unsigned int u = c.u;
  unsigned int r = (u + 0x7FFFu + ((u >> 16) & 1u)) >> 16;
  return (unsigned short)r;
}

// WT[l][e][d] = bf16(W[l][d][e])  -- 96 KB total, L2-resident afterwards
__global__ void k_wt(const float* __restrict__ W, unsigned short* __restrict__ WT) {
  __shared__ float t[64][65];
  int l = blockIdx.z, d0 = blockIdx.x * 64, e0 = blockIdx.y * 64;
  int tid = threadIdx.x;
  const float* src = W + (size_t)l * DD * DD;
  for (int p = 0; p < 16; ++p) {
    int idx = p * 256 + tid;
    int d = idx >> 6, e = idx & 63;
    t[e][d] = src[(size_t)(d0 + d) * DD + (e0 + e)];
  }
  __syncthreads();
  unsigned short* dst = WT + (size_t)l * DD * DD;
  for (int p = 0; p < 4; ++p) {
    int idx = p * 256 + tid;
    int e = idx >> 4, d4 = (idx & 15) * 4;
    ushort4 r;
    r.x = f2b(t[e][d4 + 0]); r.y = f2b(t[e][d4 + 1]);
    r.z = f2b(t[e][d4 + 2]); r.w = f2b(t[e][d4 + 3]);
    *(ushort4*)(dst + (size_t)(e0 + e) * DD + (d0 + d4)) = r;
  }
}

// Merged: x<1024 -> adj transpose tile; x>=1024 -> layer-0 gemm1 (X fp32, WT global frags)
__global__ __launch_bounds__(256) void k_pre(const float* __restrict__ adj,
                                             unsigned short* __restrict__ adjT,
                                             const float* __restrict__ X,
                                             const unsigned short* __restrict__ WT,
                                             unsigned short* __restrict__ hwT) {
  int b = blockIdx.y, x = blockIdx.x, tid = threadIdx.x;
  if (x < 1024) {
    __shared__ float t[64][65];
    int j0 = (x >> 5) * 64, i0 = (x & 31) * 64;
    const float* src = adj + (size_t)b * NN * NN;
    for (int p = 0; p < 16; ++p) {
      int idx = p * 256 + tid;
      int i = idx >> 6, j = idx & 63;
      t[j][i] = src[(size_t)(i0 + i) * NN + (j0 + j)];
    }
    __syncthreads();
    unsigned short* dst = adjT + (size_t)b * NN * NN;
    for (int p = 0; p < 4; ++p) {
      int idx = p * 256 + tid;
      int j = idx >> 4, i4 = (idx & 15) * 4;
      ushort4 r;
      r.x = f2b(t[j][i4 + 0]); r.y = f2b(t[j][i4 + 1]);
      r.z = f2b(t[j][i4 + 2]); r.w = f2b(t[j][i4 + 3]);
      *(ushort4*)(dst + (size_t)(j0 + j) * NN + (i0 + i4)) = r;
    }
  } else {
    int i0 = (x - 1024) * 64;
    int lane = tid & 63, w = tid >> 6;
    int q = lane >> 4, m = lane & 15;
    f32x4 acc[8];
#pragma unroll
    for (int t = 0; t < 8; ++t)
#pragma unroll
      for (int r = 0; r < 4; ++r) acc[t][r] = 0.f;
    int irow = i0 + w * 16 + m;
    const float* hrow = X + ((size_t)b * NN + irow) * DD;
#pragma unroll
    for (int kk = 0; kk < 4; ++kk) {
      int d0 = kk * 32 + q * 8;
      float4 h0 = *(const float4*)(hrow + d0);
      float4 h1 = *(const float4*)(hrow + d0 + 4);
      union { bf16x8 v; unsigned short s[8]; } ub;
      ub.s[0] = f2b(h0.x); ub.s[1] = f2b(h0.y); ub.s[2] = f2b(h0.z); ub.s[3] = f2b(h0.w);
      ub.s[4] = f2b(h1.x); ub.s[5] = f2b(h1.y); ub.s[6] = f2b(h1.z); ub.s[7] = f2b(h1.w);
#pragma unroll
      for (int mt = 0; mt < 8; ++mt) {
        bf16x8 af = *(const bf16x8*)(WT + (mt * 16 + m) * 128 + d0);
        acc[mt] = __builtin_amdgcn_mfma_f32_16x16x32_bf16(af, ub.v, acc[mt], 0, 0, 0);
      }
    }
    unsigned short* dst = hwT + (size_t)b * DD * NN;
#pragma unroll
    for (int mt = 0; mt < 8; ++mt)
#pragma unroll
      for (int r = 0; r < 4; ++r)
        dst[(size_t)(mt * 16 + q * 4 + r) * NN + irow] = f2b(acc[mt][r]);
  }
}

// Fused per-layer, tile 128(j)x128(e), 512 threads / 8 waves (wave-tile 32x64), K=2048.
// Triple-buffered staging, counted vmcnt(4) (T4). T3-fine intra-step interleave:
// all 12 frag ds_reads issued up front (kk0 group then kk1 group), stage-issues
// interleaved, counted lgkmcnt(6)/(0) so MFMA(kk0) overlaps kk1's ds_reads, plus
// setprio(1) around MFMA clusters (T5). Epilogue z[128][132] aliases dead staging.
__global__ __launch_bounds__(512) void k_layer(const unsigned short* __restrict__ adjT,
                                               const unsigned short* __restrict__ hwT_in,
                                               const float* __restrict__ res,
                                               const float* __restrict__ bias,
                                               const float* __restrict__ gamma,
                                               const float* __restrict__ beta,
                                               const unsigned short* __restrict__ WTn,
                                               float* __restrict__ outf,
                                               unsigned short* __restrict__ hwT_out,
                                               int doW) {
  __shared__ __align__(16) unsigned char smem[98304];  // 3 x 32768
  int tid = threadIdx.x;
  int lane = tid & 63, w = tid >> 6;          // w in 0..7
  int q = lane >> 4, m = lane & 15;
  int wj = w >> 1, we = w & 1;                // 4 x 2 wave grid -> 32x64 wave tile

  // XCD-chunked decode: 32 blocks/XCD = 2 batches' j-tiles -> hwT_in (1MB) L2-resident.
  int lin = blockIdx.x;
  int xcd = lin & 7, slot = lin >> 3;         // slot 0..31
  int b = xcd * 2 + (slot >> 4);
  int j0 = (slot & 15) * 128;

  const unsigned short* At = adjT + (size_t)b * NN * NN;
  const unsigned short* Ht = hwT_in + (size_t)b * DD * NN;

  // pre-swizzled global sources (same involution as the LDS read: cg = c ^ (r&7))
  const unsigned short* aSrc[2];
  const unsigned short* hSrc[2];
#pragma unroll
  for (int it = 0; it < 2; ++it) {
    int p = (w * 2 + it) * 64 + lane;         // chunk 0..1023 = 128 rows x 8 chunks
    int r = p >> 3, cg = (p & 7) ^ (r & 7);
    aSrc[it] = At + (size_t)(j0 + r) * NN + cg * 8;
    hSrc[it] = Ht + (size_t)r * NN + cg * 8;
  }

#define STAGE_A(bufbase)                                                              \
  do {                                                                                \
    _Pragma("unroll") for (int it = 0; it < 2; ++it) {                                \
      __builtin_amdgcn_global_load_lds((glob_u32*)aSrc[it],                           \
          (lds_u32*)((bufbase) + (w * 2 + it) * 1024 + lane * 16), 16, 0, 0);         \
      aSrc[it] += 64;                                                                 \
    }                                                                                 \
  } while (0)
#define STAGE_H(bufbase)                                                              \
  do {                                                                                \
    _Pragma("unroll") for (int it = 0; it < 2; ++it) {                                \
      __builtin_amdgcn_global_load_lds((glob_u32*)hSrc[it],                           \
          (lds_u32*)((bufbase) + 16384 + (w * 2 + it) * 1024 + lane * 16), 16, 0, 0); \
      hSrc[it] += 64;                                                                 \
    }                                                                                 \
  } while (0)

  f32x4 acc[2][4];
#pragma unroll
  for (int mt = 0; mt < 2; ++mt)
#pragma unroll
    for (int nt = 0; nt < 4; ++nt)
#pragma unroll
      for (int r = 0; r < 4; ++r) acc[mt][nt][r] = 0.f;

  STAGE_A(smem); STAGE_H(smem);                       // t=0 buf (4 in flight)
  STAGE_A(smem + 32768); STAGE_H(smem + 32768);       // t=1 buf (8 in flight)
  int rb = 0;
  for (int t = 0; t < 32; ++t) {
    // own previous-stage loads done; barrier makes ALL waves' loads visible
    if (t < 31) { asm volatile("s_waitcnt vmcnt(4)" ::: "memory"); }
    else        { asm volatile("s_waitcnt vmcnt(0)" ::: "memory"); }
    __builtin_amdgcn_sched_barrier(0);
    __builtin_amdgcn_s_barrier();
    __builtin_amdgcn_sched_barrier(0);

    const unsigned short* sA = (const unsigned short*)(smem + rb * 32768);
    const unsigned short* sH = sA + 8192;  // +16384 bytes
    int sb = rb + 2; if (sb >= 3) sb -= 3;
    unsigned char* stb = smem + sb * 32768;

    bf16x8 af0[2], bv0[4], af1[2], bv1[4];
    // kk=0 frag reads (6 ds_read_b128) -- group 1
#pragma unroll
    for (int mt = 0; mt < 2; ++mt) {
      int r = wj * 32 + mt * 16 + m;
      int c = q ^ (r & 7);
      af0[mt] = *(const bf16x8*)(sA + r * 64 + c * 8);
    }
#pragma unroll
    for (int nt = 0; nt < 4; ++nt) {
      int r = we * 64 + nt * 16 + m;
      int c = q ^ (r & 7);
      bv0[nt] = *(const bf16x8*)(sH + r * 64 + c * 8);
    }
    __builtin_amdgcn_sched_barrier(0);
    if (t < 30) STAGE_A(stb);               // vmem only: does not touch lgkmcnt
    __builtin_amdgcn_sched_barrier(0);
    // kk=1 frag reads (6 ds_read_b128) -- group 2, queued behind group 1
#pragma unroll
    for (int mt = 0; mt < 2; ++mt) {
      int r = wj * 32 + mt * 16 + m;
      int c = (4 + q) ^ (r & 7);
      af1[mt] = *(const bf16x8*)(sA + r * 64 + c * 8);
    }
#pragma unroll
    for (int nt = 0; nt < 4; ++nt) {
      int r = we * 64 + nt * 16 + m;
      int c = (4 + q) ^ (r & 7);
      bv1[nt] = *(const bf16x8*)(sH + r * 64 + c * 8);
    }
    __builtin_amdgcn_sched_barrier(0);
    // wait group 1 only (6 newer outstanding); LDS returns are in-order
    asm volatile("s_waitcnt lgkmcnt(6)" ::: "memory");
    __builtin_amdgcn_sched_barrier(0);
    __builtin_amdgcn_s_setprio(1);
#pragma unroll
    for (int mt = 0; mt < 2; ++mt)
#pragma unroll
      for (int nt = 0; nt < 4; ++nt)
        acc[mt][nt] = __builtin_amdgcn_mfma_f32_16x16x32_bf16(af0[mt], bv0[nt], acc[mt][nt], 0, 0, 0);
    __builtin_amdgcn_s_setprio(0);
    __builtin_amdgcn_sched_barrier(0);
    if (t < 30) STAGE_H(stb);
    __builtin_amdgcn_sched_barrier(0);
    asm volatile("s_waitcnt lgkmcnt(0)" ::: "memory");
    __builtin_amdgcn_sched_barrier(0);
    __builtin_amdgcn_s_setprio(1);
#pragma unroll
    for (int mt = 0; mt < 2; ++mt)
#pragma unroll
      for (int nt = 0; nt < 4; ++nt)
        acc[mt][nt] = __builtin_amdgcn_mfma_f32_16x16x32_bf16(af1[mt], bv1[nt], acc[mt][nt], 0, 0, 0);
    __builtin_amdgcn_s_setprio(0);
    rb = rb + 1; if (rb == 3) rb = 0;
  }
#undef STAGE_A
#undef STAGE_H
  __syncthreads();  // t=31 staging reads must retire before z-alias writes

  // Epilogue: staging buffers dead; alias z[128][132] f32 + smu/srs over them.
  float* z = (float*)smem;                       // 67584 B
  float* smu = (float*)(smem + 67584);           // 512 B
  float* srs = (float*)(smem + 68096);           // 512 B

  // 1) acc -> z
#pragma unroll
  for (int mt = 0; mt < 2; ++mt)
#pragma unroll
    for (int nt = 0; nt < 4; ++nt)
#pragma unroll
      for (int r = 0; r < 4; ++r) {
        int row = wj * 32 + mt * 16 + q * 4 + r;
        int col = we * 64 + nt * 16 + m;
        z[row * 132 + col] = acc[mt][nt][r];
      }
  __syncthreads();

  // 2) z += bias + res  (coalesced global reads)
  size_t base = ((size_t)b * NN + j0) * DD;
#pragma unroll
  for (int p = 0; p < 4; ++p) {
    int idx = p * 512 + tid;
    int j = idx >> 4, c8 = (idx & 15) * 8;
    const float4* r4 = (const float4*)(res + base + (size_t)j * DD + c8);
    float4 r0 = r4[0], r1 = r4[1];
    const float4* bi4 = (const float4*)(bias + c8);
    float4 b0 = bi4[0], b1 = bi4[1];
    float* zp = z + j * 132 + c8;
    zp[0] += r0.x + b0.x; zp[1] += r0.y + b0.y; zp[2] += r0.z + b0.z; zp[3] += r0.w + b0.w;
    zp[4] += r1.x + b1.x; zp[5] += r1.y + b1.y; zp[6] += r1.z + b1.z; zp[7] += r1.w + b1.w;
  }
  __syncthreads();

  // 3) LN stats: 4 threads/row, interleaved (2-way max)
  {
    int j = tid >> 2, s = tid & 3;
    float sum = 0.f, sq = 0.f;
#pragma unroll
    for (int k = 0; k < 32; ++k) {
      float v = z[j * 132 + s + 4 * k];
      sum += v; sq += v * v;
    }
    sum += __shfl_xor(sum, 1); sq += __shfl_xor(sq, 1);
    sum += __shfl_xor(sum, 2); sq += __shfl_xor(sq, 2);
    if (s == 0) {
      float mu = sum * (1.f / 128.f);
      float var = sq * (1.f / 128.f) - mu * mu;
      smu[j] = mu;
      srs[j] = rsqrtf(var + 1e-5f);
    }
  }
  __syncthreads();

  // 4) normalize + ReLU -> out (coalesced) and back into z for gemm1
  {
    int e = tid & 127;
    float g = gamma[e], bt = beta[e];
#pragma unroll
    for (int p = 0; p < 32; ++p) {
      int idx = p * 512 + tid;
      int j = idx >> 7;
      float v = (z[j * 132 + e] - smu[j]) * srs[j] * g + bt;
      v = fmaxf(v, 0.f);
      outf[base + idx] = v;
      z[j * 132 + e] = v;   // same thread, same slot: no race
    }
  }
  if (!doW) return;
  __syncthreads();

  // 5) gemm1: hwT_out[e'][j0+row] = (h @ Wn)^T ; 8 waves x 16 rows each.
  f32x4 a2[8];
#pragma unroll
  for (int t = 0; t < 8; ++t)
#pragma unroll
    for (int r = 0; r < 4; ++r) a2[t][r] = 0.f;
  const float* hrow = z + (w * 16 + m) * 132;
#pragma unroll
  for (int kk = 0; kk < 4; ++kk) {
    int d0 = kk * 32 + q * 8;
    float4 h0 = *(const float4*)(hrow + d0);
    float4 h1 = *(const float4*)(hrow + d0 + 4);
    union { bf16x8 v; unsigned short s[8]; } ub;
    ub.s[0] = f2b(h0.x); ub.s[1] = f2b(h0.y); ub.s[2] = f2b(h0.z); ub.s[3] = f2b(h0.w);
    ub.s[4] = f2b(h1.x); ub.s[5] = f2b(h1.y); ub.s[6] = f2b(h1.z); ub.s[7] = f2b(h1.w);
#pragma unroll
    for (int mt = 0; mt < 8; ++mt) {
      bf16x8 af = *(const bf16x8*)(WTn + (mt * 16 + m) * 128 + d0);
      a2[mt] = __builtin_amdgcn_mfma_f32_16x16x32_bf16(af, ub.v, a2[mt], 0, 0, 0);
    }
  }
  unsigned short* dst = hwT_out + (size_t)b * DD * NN;
  int irow = j0 + w * 16 + m;
#pragma unroll
  for (int mt = 0; mt < 8; ++mt)
#pragma unroll
    for (int r = 0; r < 4; ++r)
      dst[(size_t)(mt * 16 + q * 4 + r) * NN + irow] = f2b(a2[mt][r]);
}

extern "C" void kernel_launch(void* const* d_in, const int* in_sizes, int n_in,
                              void* d_out, int out_size, void* d_ws, size_t ws_size,
                              hipStream_t stream) {
  const float* X   = (const float*)d_in[0];
  const float* adj = (const float*)d_in[1];
  const float* Ws  = (const float*)d_in[2];
  const float* bs  = (const float*)d_in[3];
  const float* gms = (const float*)d_in[4];
  const float* bts = (const float*)d_in[5];
  float* out = (float*)d_out;

  // ws: adjT bf16 (134MB) | hwT_A (8.4MB) | hwT_B (8.4MB) | WT bf16 (96KB)
  unsigned short* adjT = (unsigned short*)d_ws;
  unsigned short* hwTA = adjT + (size_t)BB * NN * NN;
  unsigned short* hwTB = hwTA + (size_t)BB * DD * NN;
  unsigned short* WT   = hwTB + (size_t)BB * DD * NN;

  k_wt<<<dim3(2, 2, 3), 256, 0, stream>>>(Ws, WT);
  k_pre<<<dim3(1056, BB), 256, 0, stream>>>(adj, adjT, X, WT, hwTA);
  unsigned short* hin = hwTA;
  unsigned short* hout = hwTB;
  for (int l = 0; l < 3; ++l) {
    const float* res = (l == 0) ? X : (const float*)out;
    const unsigned short* WTn = WT + (size_t)((l < 2) ? (l + 1) : 0) * DD * DD;
    k_layer<<<dim3(256), 512, 0, stream>>>(adjT, hin, res, bs + l * DD,
                                           gms + l * DD, bts + l * DD,
                                           WTn, out, hout, (l < 2) ? 1 : 0);
    unsigned short* tmp = hin; hin = hout; hout = tmp;
  }
}